// Round 1
// baseline (3528.474 us; speedup 1.0000x reference)
//
#include <hip/hip_runtime.h>
#include <math.h>

#define BS  4
#define LSEQ 512
#define DM  256
#define DIc 512
#define DSt 32
#define DTR 16
#define NLAY 6
#define NCLS 50
#define PATCH 160

__device__ __forceinline__ float sigmoidf_(float x){ return 1.f/(1.f+__expf(-x)); }
__device__ __forceinline__ float siluf_(float x){ return x*sigmoidf_(x); }
__device__ __forceinline__ float softplusf_(float x){ return fmaxf(x,0.f) + log1pf(expf(-fabsf(x))); }

// ---------------- LayerNorm over last dim (256), one block (256 thr) per row ----
__global__ __launch_bounds__(256) void ln_k(const float* __restrict__ in,
                                            const float* __restrict__ g,
                                            const float* __restrict__ bta,
                                            float* __restrict__ out)
{
    int row = blockIdx.x;
    int c = threadIdx.x;
    float v = in[(long)row*DM + c];
    __shared__ float red[4];
    __shared__ float mu_s, rs_s;
    float s = v;
    #pragma unroll
    for (int o = 32; o; o >>= 1) s += __shfl_down(s, o);
    if ((threadIdx.x & 63) == 0) red[threadIdx.x >> 6] = s;
    __syncthreads();
    if (threadIdx.x == 0) mu_s = (red[0]+red[1]+red[2]+red[3]) * (1.f/DM);
    __syncthreads();
    float mu = mu_s;
    float d0 = v - mu;
    float q = d0*d0;
    #pragma unroll
    for (int o = 32; o; o >>= 1) q += __shfl_down(q, o);
    if ((threadIdx.x & 63) == 0) red[threadIdx.x >> 6] = q;
    __syncthreads();
    if (threadIdx.x == 0) rs_s = rsqrtf((red[0]+red[1]+red[2]+red[3]) * (1.f/DM) + 1e-5f);
    __syncthreads();
    out[(long)row*DM + c] = d0 * rs_s * g[c] + bta[c];
}

// ---------------- Patch conv (stride 160, kernel 160) + bias + LayerNorm -------
__global__ __launch_bounds__(256) void patch_k(const float* __restrict__ x,
                                               const float* __restrict__ pw,
                                               const float* __restrict__ pb,
                                               const float* __restrict__ g,
                                               const float* __restrict__ bta,
                                               float* __restrict__ out)
{
    int bl = blockIdx.x;            // b*LSEQ + l
    int b = bl >> 9, l = bl & 511;
    __shared__ float xs[PATCH];
    if (threadIdx.x < PATCH) xs[threadIdx.x] = x[(long)b*81920 + l*PATCH + threadIdx.x];
    __syncthreads();
    int c = threadIdx.x;
    float acc = pb[c];
    const float* w = pw + (long)c*PATCH;
    #pragma unroll 4
    for (int k = 0; k < PATCH; ++k) acc = fmaf(xs[k], w[k], acc);
    // LN across block
    __shared__ float red[4];
    __shared__ float mu_s, rs_s;
    float s = acc;
    #pragma unroll
    for (int o = 32; o; o >>= 1) s += __shfl_down(s, o);
    if ((threadIdx.x & 63) == 0) red[threadIdx.x >> 6] = s;
    __syncthreads();
    if (threadIdx.x == 0) mu_s = (red[0]+red[1]+red[2]+red[3]) * (1.f/DM);
    __syncthreads();
    float mu = mu_s;
    float d0 = acc - mu;
    float q = d0*d0;
    #pragma unroll
    for (int o = 32; o; o >>= 1) q += __shfl_down(q, o);
    if ((threadIdx.x & 63) == 0) red[threadIdx.x >> 6] = q;
    __syncthreads();
    if (threadIdx.x == 0) rs_s = rsqrtf((red[0]+red[1]+red[2]+red[3]) * (1.f/DM) + 1e-5f);
    __syncthreads();
    out[(long)bl*DM + c] = d0 * rs_s * g[c] + bta[c];
}

// ---------------- Generic tiled fp32 GEMM --------------------------------------
// C[z] = epilogue( A[z] (MxK, lda) @ Bw[z] (KxN, ldb) )
// AMODE 0: a = A[r,k];  AMODE 1: a = A[r,k] * silu(A2[r,k])
// EMODE 0: C = acc; EMODE 1: C = softplus(acc + bias); EMODE 2: C = acc + bias + Res
#define BM 64
#define BN 64
#define BK 16
template<int AMODE, int EMODE>
__global__ __launch_bounds__(256) void gemm_k(
    const float* __restrict__ A,  long aZ, int lda,
    const float* __restrict__ A2, long a2Z, int lda2,
    const float* __restrict__ Bw, long bZ, int ldb,
    const float* __restrict__ bias, long biasZ,
    const float* __restrict__ Res, int ldres,
    float* __restrict__ C, long cZ, int ldc,
    int M, int N, int K)
{
    int z = blockIdx.z;
    A += (long)z * aZ;
    if (AMODE == 1) A2 += (long)z * a2Z;
    Bw += (long)z * bZ;
    if (EMODE >= 1) bias += (long)z * biasZ;
    C += (long)z * cZ;

    __shared__ float As[BK][BM+4];
    __shared__ float Bs[BK][BN];
    int row0 = blockIdx.y * BM, col0 = blockIdx.x * BN;
    int tx = threadIdx.x & 15, ty = threadIdx.x >> 4;
    float acc[4][4] = {};

    for (int k0 = 0; k0 < K; k0 += BK) {
        #pragma unroll
        for (int e = 0; e < 4; ++e) {
            int idx = e*256 + threadIdx.x;
            int m = idx >> 4, kk = idx & 15;
            int gr = row0 + m, gk = k0 + kk;
            float v = 0.f;
            if (gr < M && gk < K) {
                v = A[(long)gr*lda + gk];
                if (AMODE == 1) v *= siluf_(A2[(long)gr*lda2 + gk]);
            }
            As[kk][m] = v;
        }
        #pragma unroll
        for (int e = 0; e < 4; ++e) {
            int idx = e*256 + threadIdx.x;
            int kk = idx >> 6, n = idx & 63;
            int gk = k0 + kk, gn = col0 + n;
            float v = 0.f;
            if (gk < K && gn < N) v = Bw[(long)gk*ldb + gn];
            Bs[kk][n] = v;
        }
        __syncthreads();
        #pragma unroll
        for (int kk = 0; kk < BK; ++kk) {
            float4 av = *reinterpret_cast<const float4*>(&As[kk][ty*4]);
            float4 bv = *reinterpret_cast<const float4*>(&Bs[kk][tx*4]);
            float a[4] = {av.x, av.y, av.z, av.w};
            float b[4] = {bv.x, bv.y, bv.z, bv.w};
            #pragma unroll
            for (int i = 0; i < 4; ++i)
                #pragma unroll
                for (int j = 0; j < 4; ++j)
                    acc[i][j] = fmaf(a[i], b[j], acc[i][j]);
        }
        __syncthreads();
    }

    #pragma unroll
    for (int i = 0; i < 4; ++i) {
        int gr = row0 + ty*4 + i;
        if (gr >= M) continue;
        #pragma unroll
        for (int j = 0; j < 4; ++j) {
            int gn = col0 + tx*4 + j;
            if (gn >= N) continue;
            float v = acc[i][j];
            if (EMODE == 1)      v = softplusf_(v + bias[gn]);
            else if (EMODE == 2) v = v + bias[gn] + Res[(long)gr*ldres + gn];
            C[(long)gr*ldc + gn] = v;
        }
    }
}

// ---------------- Depthwise causal conv (k=4) + bias + SiLU, scan-order output --
// xz layout [2][BS][LSEQ(t orig)][1024]; xc layout [2][BS][LSEQ(s scan)][DIc]
__global__ __launch_bounds__(256) void conv_silu_k(const float* __restrict__ xz,
                                                   const float* __restrict__ cw,
                                                   const float* __restrict__ cb,
                                                   float* __restrict__ xc)
{
    long idx = (long)blockIdx.x * 256 + threadIdx.x;  // [2][BS][LSEQ][DIc]
    int d   = idx & 511;
    int s   = (idx >> 9) & 511;
    int b   = (idx >> 18) & 3;
    int dir = (int)(idx >> 20);
    const float* xp = xz + (((long)dir*BS + b) * LSEQ) * 1024;
    float acc = cb[dir*DIc + d];
    const float* w = cw + ((long)dir*DIc + d) * 4;
    #pragma unroll
    for (int j = 0; j < 4; ++j) {
        int m = s - 3 + j;
        if (m >= 0) {
            int t = dir ? (LSEQ-1 - m) : m;
            acc = fmaf(w[j], xp[(long)t*1024 + d], acc);
        }
    }
    xc[idx] = siluf_(acc);
}

// ---------------- Selective scan ------------------------------------------------
// 32 lanes = one (dir,b,d) channel's 32 states. 256 thr = 8 channels/block.
__global__ __launch_bounds__(256) void scan_k(const float* __restrict__ dt,   // [2][BS][LSEQ s][DIc]
                                              const float* __restrict__ u,    // xc, same layout
                                              const float* __restrict__ xdbl, // [2][BS][LSEQ s][80]
                                              const float* __restrict__ A_log,// [2][DIc][32]
                                              const float* __restrict__ Dv,   // [2][DIc]
                                              float* __restrict__ y)          // [2][BS][LSEQ t orig][DIc]
{
    int dir = blockIdx.z, b = blockIdx.y;
    int n = threadIdx.x & 31;
    int d = blockIdx.x * 8 + (threadIdx.x >> 5);
    float Adn = -__expf(A_log[((long)dir*DIc + d)*DSt + n]);
    float Dd  = Dv[dir*DIc + d];
    long base = (((long)dir*BS + b) * LSEQ);
    const float* dtp = dt   + base*DIc + d;
    const float* up  = u    + base*DIc + d;
    const float* xdp = xdbl + base*80;
    float* yp = y + base*DIc + d;
    float h = 0.f;
    #pragma unroll 4
    for (int s = 0; s < LSEQ; ++s) {
        float dtv = dtp[(long)s*DIc];
        float uv  = up[(long)s*DIc];
        float Bn  = xdp[s*80 + 16 + n];
        float Cn  = xdp[s*80 + 48 + n];
        float da  = __expf(dtv * Adn);
        h = fmaf(da, h, dtv*uv*Bn);
        float p = h * Cn;
        p += __shfl_xor(p, 1, 32);
        p += __shfl_xor(p, 2, 32);
        p += __shfl_xor(p, 4, 32);
        p += __shfl_xor(p, 8, 32);
        p += __shfl_xor(p, 16, 32);
        if (n == 0) {
            int t = dir ? (LSEQ-1 - s) : s;
            yp[(long)t*DIc] = fmaf(uv, Dd, p);
        }
    }
}

// ---------------- Head: mean over L then @ cls_w + cls_b ------------------------
__global__ __launch_bounds__(256) void head_k(const float* __restrict__ hn,
                                              const float* __restrict__ cw,
                                              const float* __restrict__ cb2,
                                              float* __restrict__ out)
{
    int b = blockIdx.x;
    int c = threadIdx.x;
    float acc = 0.f;
    for (int t = 0; t < LSEQ; ++t) acc += hn[((long)b*LSEQ + t)*DM + c];
    __shared__ float mv[DM];
    mv[c] = acc * (1.f/LSEQ);
    __syncthreads();
    if (c < NCLS) {
        float o = cb2[c];
        #pragma unroll 4
        for (int k = 0; k < DM; ++k) o = fmaf(mv[k], cw[k*NCLS + c], o);
        out[b*NCLS + c] = o;
    }
}

extern "C" void kernel_launch(void* const* d_in, const int* in_sizes, int n_in,
                              void* d_out, int out_size, void* d_ws, size_t ws_size,
                              hipStream_t stream)
{
    const float* x        = (const float*)d_in[0];
    const float* patch_w  = (const float*)d_in[1];
    const float* patch_b  = (const float*)d_in[2];
    const float* in_g     = (const float*)d_in[3];
    const float* in_b     = (const float*)d_in[4];
    const float* ln_g     = (const float*)d_in[5];
    const float* ln_b     = (const float*)d_in[6];
    const float* in_proj_w= (const float*)d_in[7];
    const float* conv_w   = (const float*)d_in[8];
    const float* conv_b   = (const float*)d_in[9];
    const float* x_proj_w = (const float*)d_in[10];
    const float* dt_proj_w= (const float*)d_in[11];
    const float* dt_proj_b= (const float*)d_in[12];
    const float* A_log    = (const float*)d_in[13];
    const float* Dv       = (const float*)d_in[14];
    const float* m_out_w  = (const float*)d_in[15];
    const float* blk_out_w= (const float*)d_in[16];
    const float* blk_out_b= (const float*)d_in[17];
    const float* fin_g    = (const float*)d_in[18];
    const float* fin_b    = (const float*)d_in[19];
    const float* cls_w    = (const float*)d_in[20];
    const float* cls_b    = (const float*)d_in[21];

    const int M = BS * LSEQ;             // 2048 rows
    float* ws  = (float*)d_ws;
    float* h   = ws;                      // 524288
    float* hn  = h   + (long)M*DM;        // 524288
    float* xz  = hn  + (long)M*DM;        // 2*2048*1024 = 4194304
    float* xc  = xz  + (long)2*M*1024;    // 2*2048*512  = 2097152
    float* xdb = xc  + (long)2*M*DIc;     // 2*2048*80   = 327680
    float* dtb = xdb + (long)2*M*80;      // 2*2048*512  = 2097152
    float* yb  = dtb + (long)2*M*DIc;     // 2*2048*512  = 2097152
    float* mo  = yb  + (long)2*M*DIc;     // 2048*512    = 1048576

    // patch embed + input LN -> h
    patch_k<<<M, 256, 0, stream>>>(x, patch_w, patch_b, in_g, in_b, h);

    for (int i = 0; i < NLAY; ++i) {
        const float* ipw = in_proj_w + (long)i*2*DM*1024;
        const float* cw  = conv_w    + (long)i*2*DIc*4;
        const float* cb  = conv_b    + (long)i*2*DIc;
        const float* xpw = x_proj_w  + (long)i*2*DIc*80;
        const float* dtw = dt_proj_w + (long)i*2*DTR*DIc;
        const float* dtbias = dt_proj_b + (long)i*2*DIc;
        const float* Al  = A_log     + (long)i*2*DIc*DSt;
        const float* Dvp = Dv        + (long)i*2*DIc;
        const float* mow = m_out_w   + (long)i*2*DIc*DM;
        const float* bow = blk_out_w + (long)i*DIc*DM;
        const float* bob = blk_out_b + (long)i*DM;

        // hn = LN(h)
        ln_k<<<M, 256, 0, stream>>>(h, ln_g + i*DM, ln_b + i*DM, hn);

        // xz[dir] = hn @ in_proj_w[i,dir]   (M=2048, K=256, N=1024)
        gemm_k<0,0><<<dim3(1024/BN, M/BM, 2), 256, 0, stream>>>(
            hn, 0, DM,  nullptr, 0, 0,
            ipw, (long)DM*1024, 1024,
            nullptr, 0, nullptr, 0,
            xz, (long)M*1024, 1024, M, 1024, DM);

        // xc[dir] (scan order) = silu(depthwise_causal_conv(xpart) + cb)
        conv_silu_k<<<(2L*M*DIc)/256, 256, 0, stream>>>(xz, cw, cb, xc);

        // xdbl[dir] = xc @ x_proj_w[i,dir]  (M=2048, K=512, N=80)
        gemm_k<0,0><<<dim3(2, M/BM, 2), 256, 0, stream>>>(
            xc, (long)M*DIc, DIc,  nullptr, 0, 0,
            xpw, (long)DIc*80, 80,
            nullptr, 0, nullptr, 0,
            xdb, (long)M*80, 80, M, 80, DIc);

        // dt = softplus(xdbl[:, :16] @ dt_proj_w + dt_proj_b)  (M=2048, K=16, N=512)
        gemm_k<0,1><<<dim3(DIc/BN, M/BM, 2), 256, 0, stream>>>(
            xdb, (long)M*80, 80,  nullptr, 0, 0,
            dtw, (long)DTR*DIc, DIc,
            dtbias, DIc, nullptr, 0,
            dtb, (long)M*DIc, DIc, M, DIc, DTR);

        // selective scan -> yb (original time order), includes +xc*Dv
        scan_k<<<dim3(DIc/8, BS, 2), 256, 0, stream>>>(dtb, xc, xdb, Al, Dvp, yb);

        // mo[:, dir*256:(dir+1)*256] = (yb * silu(z)) @ m_out_w[i,dir]
        gemm_k<1,0><<<dim3(DM/BN, M/BM, 2), 256, 0, stream>>>(
            yb, (long)M*DIc, DIc,
            xz + DIc, (long)M*1024, 1024,      // z = xz[..., 512:]
            mow, (long)DIc*DM, DM,
            nullptr, 0, nullptr, 0,
            mo, DM, DIc, M, DM, DIc);

        // h = mo @ blk_out_w[i] + blk_out_b[i] + h   (M=2048, K=512, N=256)
        gemm_k<0,2><<<dim3(DM/BN, M/BM, 1), 256, 0, stream>>>(
            mo, 0, DIc,  nullptr, 0, 0,
            bow, 0, DM,
            bob, 0, h, DM,
            h, 0, DM, M, DM, DIc);
    }

    // final LN + head
    ln_k<<<M, 256, 0, stream>>>(h, fin_g, fin_b, hn);
    head_k<<<BS, 256, 0, stream>>>(hn, cls_w, cls_b, (float*)d_out);
}

// Round 2
// 1896.766 us; speedup vs baseline: 1.8603x; 1.8603x over previous
//
#include <hip/hip_runtime.h>
#include <math.h>

#define BS  4
#define LSEQ 512
#define DM  256
#define DIc 512
#define DSt 32
#define DTR 16
#define NLAY 6
#define NCLS 50
#define PATCH 160

__device__ __forceinline__ float sigmoidf_(float x){ return 1.f/(1.f+__expf(-x)); }
__device__ __forceinline__ float siluf_(float x){ return x*sigmoidf_(x); }
__device__ __forceinline__ float softplusf_(float x){ return fmaxf(x,0.f) + log1pf(expf(-fabsf(x))); }

// ---------------- LayerNorm over last dim (256), one block (256 thr) per row ----
__global__ __launch_bounds__(256) void ln_k(const float* __restrict__ in,
                                            const float* __restrict__ g,
                                            const float* __restrict__ bta,
                                            float* __restrict__ out)
{
    int row = blockIdx.x;
    int c = threadIdx.x;
    float v = in[(long)row*DM + c];
    __shared__ float red[4];
    __shared__ float mu_s, rs_s;
    float s = v;
    #pragma unroll
    for (int o = 32; o; o >>= 1) s += __shfl_down(s, o);
    if ((threadIdx.x & 63) == 0) red[threadIdx.x >> 6] = s;
    __syncthreads();
    if (threadIdx.x == 0) mu_s = (red[0]+red[1]+red[2]+red[3]) * (1.f/DM);
    __syncthreads();
    float mu = mu_s;
    float d0 = v - mu;
    float q = d0*d0;
    #pragma unroll
    for (int o = 32; o; o >>= 1) q += __shfl_down(q, o);
    if ((threadIdx.x & 63) == 0) red[threadIdx.x >> 6] = q;
    __syncthreads();
    if (threadIdx.x == 0) rs_s = rsqrtf((red[0]+red[1]+red[2]+red[3]) * (1.f/DM) + 1e-5f);
    __syncthreads();
    out[(long)row*DM + c] = d0 * rs_s * g[c] + bta[c];
}

// ---------------- Patch conv (stride 160, kernel 160) + bias + LayerNorm -------
__global__ __launch_bounds__(256) void patch_k(const float* __restrict__ x,
                                               const float* __restrict__ pw,
                                               const float* __restrict__ pb,
                                               const float* __restrict__ g,
                                               const float* __restrict__ bta,
                                               float* __restrict__ out)
{
    int bl = blockIdx.x;            // b*LSEQ + l
    int b = bl >> 9, l = bl & 511;
    __shared__ float xs[PATCH];
    if (threadIdx.x < PATCH) xs[threadIdx.x] = x[(long)b*81920 + l*PATCH + threadIdx.x];
    __syncthreads();
    int c = threadIdx.x;
    float acc = pb[c];
    const float* w = pw + (long)c*PATCH;
    #pragma unroll 4
    for (int k = 0; k < PATCH; ++k) acc = fmaf(xs[k], w[k], acc);
    // LN across block
    __shared__ float red[4];
    __shared__ float mu_s, rs_s;
    float s = acc;
    #pragma unroll
    for (int o = 32; o; o >>= 1) s += __shfl_down(s, o);
    if ((threadIdx.x & 63) == 0) red[threadIdx.x >> 6] = s;
    __syncthreads();
    if (threadIdx.x == 0) mu_s = (red[0]+red[1]+red[2]+red[3]) * (1.f/DM);
    __syncthreads();
    float mu = mu_s;
    float d0 = acc - mu;
    float q = d0*d0;
    #pragma unroll
    for (int o = 32; o; o >>= 1) q += __shfl_down(q, o);
    if ((threadIdx.x & 63) == 0) red[threadIdx.x >> 6] = q;
    __syncthreads();
    if (threadIdx.x == 0) rs_s = rsqrtf((red[0]+red[1]+red[2]+red[3]) * (1.f/DM) + 1e-5f);
    __syncthreads();
    out[(long)bl*DM + c] = d0 * rs_s * g[c] + bta[c];
}

// ---------------- Generic tiled fp32 GEMM, double-buffered LDS ------------------
// C[z] = epilogue( A[z] (MxK, lda) @ Bw[z] (KxN, ldb) )
// AMODE 0: a = A[r,k];  AMODE 1: a = A[r,k] * silu(A2[r,k])
// EMODE 0: C = acc; EMODE 1: C = softplus(acc + bias); EMODE 2: C = acc + bias + Res
#define BM 64
#define BN 64
#define BK 16
template<int AMODE, int EMODE>
__global__ __launch_bounds__(256) void gemm_k(
    const float* __restrict__ A,  long aZ, int lda,
    const float* __restrict__ A2, long a2Z, int lda2,
    const float* __restrict__ Bw, long bZ, int ldb,
    const float* __restrict__ bias, long biasZ,
    const float* __restrict__ Res, int ldres,
    float* __restrict__ C, long cZ, int ldc,
    int M, int N, int K)
{
    int z = blockIdx.z;
    A += (long)z * aZ;
    if (AMODE == 1) A2 += (long)z * a2Z;
    Bw += (long)z * bZ;
    if (EMODE >= 1) bias += (long)z * biasZ;
    C += (long)z * cZ;

    __shared__ float As[2][BK][BM+4];
    __shared__ float Bs[2][BK][BN];
    int row0 = blockIdx.y * BM, col0 = blockIdx.x * BN;
    int tx = threadIdx.x & 15, ty = threadIdx.x >> 4;
    float acc[4][4] = {};

    // stage tile k0=0 into buffer 0
    {
        #pragma unroll
        for (int e = 0; e < 4; ++e) {
            int idx = e*256 + threadIdx.x;
            int m = idx >> 4, kk = idx & 15;
            int gr = row0 + m, gk = kk;
            float v = 0.f;
            if (gr < M && gk < K) {
                v = A[(long)gr*lda + gk];
                if (AMODE == 1) v *= siluf_(A2[(long)gr*lda2 + gk]);
            }
            As[0][kk][m] = v;
            int kb = idx >> 6, nn = idx & 63;
            int gn = col0 + nn;
            Bs[0][kb][nn] = (kb < K && gn < N) ? Bw[(long)kb*ldb + gn] : 0.f;
        }
    }
    __syncthreads();

    int nbuf = 1;
    for (int k0 = 0; k0 < K; k0 += BK) {
        int cur = nbuf ^ 1;
        bool more = (k0 + BK) < K;
        float ra[4], rb[4];
        if (more) {
            #pragma unroll
            for (int e = 0; e < 4; ++e) {
                int idx = e*256 + threadIdx.x;
                int m = idx >> 4, kk = idx & 15;
                int gr = row0 + m, gk = k0 + BK + kk;
                float v = 0.f;
                if (gr < M && gk < K) {
                    v = A[(long)gr*lda + gk];
                    if (AMODE == 1) v *= siluf_(A2[(long)gr*lda2 + gk]);
                }
                ra[e] = v;
                int kb = idx >> 6, nn = idx & 63;
                int gk2 = k0 + BK + kb, gn = col0 + nn;
                rb[e] = (gk2 < K && gn < N) ? Bw[(long)gk2*ldb + gn] : 0.f;
            }
        }
        #pragma unroll
        for (int kk = 0; kk < BK; ++kk) {
            float4 av = *reinterpret_cast<const float4*>(&As[cur][kk][ty*4]);
            float4 bv = *reinterpret_cast<const float4*>(&Bs[cur][kk][tx*4]);
            float a[4] = {av.x, av.y, av.z, av.w};
            float b[4] = {bv.x, bv.y, bv.z, bv.w};
            #pragma unroll
            for (int i = 0; i < 4; ++i)
                #pragma unroll
                for (int j = 0; j < 4; ++j)
                    acc[i][j] = fmaf(a[i], b[j], acc[i][j]);
        }
        if (more) {
            #pragma unroll
            for (int e = 0; e < 4; ++e) {
                int idx = e*256 + threadIdx.x;
                As[nbuf][idx & 15][idx >> 4] = ra[e];
                Bs[nbuf][idx >> 6][idx & 63] = rb[e];
            }
        }
        __syncthreads();
        nbuf ^= 1;
    }

    #pragma unroll
    for (int i = 0; i < 4; ++i) {
        int gr = row0 + ty*4 + i;
        if (gr >= M) continue;
        #pragma unroll
        for (int j = 0; j < 4; ++j) {
            int gn = col0 + tx*4 + j;
            if (gn >= N) continue;
            float v = acc[i][j];
            if (EMODE == 1)      v = softplusf_(v + bias[gn]);
            else if (EMODE == 2) v = v + bias[gn] + Res[(long)gr*ldres + gn];
            C[(long)gr*ldc + gn] = v;
        }
    }
}

// ---------------- Depthwise causal conv (k=4) + bias + SiLU, scan-order output --
// xz layout [2][BS][LSEQ(t orig)][1024]; xc layout [2][BS][LSEQ(s scan)][DIc]
__global__ __launch_bounds__(256) void conv_silu_k(const float* __restrict__ xz,
                                                   const float* __restrict__ cw,
                                                   const float* __restrict__ cb,
                                                   float* __restrict__ xc)
{
    long idx = (long)blockIdx.x * 256 + threadIdx.x;  // [2][BS][LSEQ][DIc]
    int d   = idx & 511;
    int s   = (idx >> 9) & 511;
    int b   = (idx >> 18) & 3;
    int dir = (int)(idx >> 20);
    const float* xp = xz + (((long)dir*BS + b) * LSEQ) * 1024;
    float acc = cb[dir*DIc + d];
    const float* w = cw + ((long)dir*DIc + d) * 4;
    #pragma unroll
    for (int j = 0; j < 4; ++j) {
        int m = s - 3 + j;
        if (m >= 0) {
            int t = dir ? (LSEQ-1 - m) : m;
            acc = fmaf(w[j], xp[(long)t*1024 + d], acc);
        }
    }
    xc[idx] = siluf_(acc);
}

// ---------------- Selective scan, software-pipelined ---------------------------
// 32 lanes = one (dir,b,d) channel's 32 states. 256 thr = 8 channels/block.
// Chunks of TCH=8 timesteps; next chunk's operands prefetched into registers
// while current chunk computes; reductions batched for ILP.
#define TCH 8
__global__ __launch_bounds__(256) void scan_k(const float* __restrict__ dt,   // [2][BS][LSEQ s][DIc]
                                              const float* __restrict__ u,    // xc, same layout
                                              const float* __restrict__ xdbl, // [2][BS][LSEQ s][80]
                                              const float* __restrict__ A_log,// [2][DIc][32]
                                              const float* __restrict__ Dv,   // [2][DIc]
                                              float* __restrict__ y)          // [2][BS][LSEQ t orig][DIc]
{
    int dir = blockIdx.z, b = blockIdx.y;
    int n = threadIdx.x & 31;
    int d = blockIdx.x * 8 + (threadIdx.x >> 5);
    float Adn = -__expf(A_log[((long)dir*DIc + d)*DSt + n]);
    float Dd  = Dv[dir*DIc + d];
    long base = (((long)dir*BS + b) * LSEQ);
    const float* dtp = dt   + base*DIc + d;
    const float* up  = u    + base*DIc + d;
    const float* xdp = xdbl + base*80;
    float* yp = y + base*DIc + d;

    float cdt[TCH], cu[TCH], cB[TCH], cC[TCH];
    float ndt[TCH], nu[TCH], nB[TCH], nC[TCH];
    #pragma unroll
    for (int j = 0; j < TCH; ++j) {
        cdt[j] = dtp[(long)j*DIc];
        cu[j]  = up[(long)j*DIc];
        cB[j]  = xdp[j*80 + 16 + n];
        cC[j]  = xdp[j*80 + 48 + n];
    }

    float h = 0.f;
    for (int s0 = 0; s0 < LSEQ; s0 += TCH) {
        int s1 = s0 + TCH;
        bool more = s1 < LSEQ;
        if (more) {
            #pragma unroll
            for (int j = 0; j < TCH; ++j) {
                ndt[j] = dtp[(long)(s1+j)*DIc];
                nu[j]  = up[(long)(s1+j)*DIc];
                nB[j]  = xdp[(s1+j)*80 + 16 + n];
                nC[j]  = xdp[(s1+j)*80 + 48 + n];
            }
        }
        // off-chain: decay and input terms (independent, good ILP)
        float da[TCH], bu[TCH], p[TCH];
        #pragma unroll
        for (int j = 0; j < TCH; ++j) {
            da[j] = __expf(cdt[j]*Adn);
            bu[j] = cdt[j]*cu[j]*cB[j];
        }
        // serial recurrence (the only true dependence chain)
        #pragma unroll
        for (int j = 0; j < TCH; ++j) {
            h = fmaf(da[j], h, bu[j]);
            p[j] = h * cC[j];
        }
        // batched butterfly reductions over the 32 state lanes
        #pragma unroll
        for (int st = 1; st < 32; st <<= 1) {
            #pragma unroll
            for (int j = 0; j < TCH; ++j)
                p[j] += __shfl_xor(p[j], st, 32);
        }
        // lane j (<TCH) emits y for step s0+j (all lanes hold all sums)
        float outv = 0.f;
        #pragma unroll
        for (int j = 0; j < TCH; ++j)
            if (n == j) outv = fmaf(cu[j], Dd, p[j]);
        if (n < TCH) {
            int t = dir ? (LSEQ-1 - (s0 + n)) : (s0 + n);
            yp[(long)t*DIc] = outv;
        }
        if (more) {
            #pragma unroll
            for (int j = 0; j < TCH; ++j) {
                cdt[j]=ndt[j]; cu[j]=nu[j]; cB[j]=nB[j]; cC[j]=nC[j];
            }
        }
    }
}

// ---------------- Head: mean over L then @ cls_w + cls_b ------------------------
__global__ __launch_bounds__(256) void head_k(const float* __restrict__ hn,
                                              const float* __restrict__ cw,
                                              const float* __restrict__ cb2,
                                              float* __restrict__ out)
{
    int b = blockIdx.x;
    int c = threadIdx.x;
    float acc = 0.f;
    for (int t = 0; t < LSEQ; ++t) acc += hn[((long)b*LSEQ + t)*DM + c];
    __shared__ float mv[DM];
    mv[c] = acc * (1.f/LSEQ);
    __syncthreads();
    if (c < NCLS) {
        float o = cb2[c];
        #pragma unroll 4
        for (int k = 0; k < DM; ++k) o = fmaf(mv[k], cw[k*NCLS + c], o);
        out[b*NCLS + c] = o;
    }
}

extern "C" void kernel_launch(void* const* d_in, const int* in_sizes, int n_in,
                              void* d_out, int out_size, void* d_ws, size_t ws_size,
                              hipStream_t stream)
{
    const float* x        = (const float*)d_in[0];
    const float* patch_w  = (const float*)d_in[1];
    const float* patch_b  = (const float*)d_in[2];
    const float* in_g     = (const float*)d_in[3];
    const float* in_b     = (const float*)d_in[4];
    const float* ln_g     = (const float*)d_in[5];
    const float* ln_b     = (const float*)d_in[6];
    const float* in_proj_w= (const float*)d_in[7];
    const float* conv_w   = (const float*)d_in[8];
    const float* conv_b   = (const float*)d_in[9];
    const float* x_proj_w = (const float*)d_in[10];
    const float* dt_proj_w= (const float*)d_in[11];
    const float* dt_proj_b= (const float*)d_in[12];
    const float* A_log    = (const float*)d_in[13];
    const float* Dv       = (const float*)d_in[14];
    const float* m_out_w  = (const float*)d_in[15];
    const float* blk_out_w= (const float*)d_in[16];
    const float* blk_out_b= (const float*)d_in[17];
    const float* fin_g    = (const float*)d_in[18];
    const float* fin_b    = (const float*)d_in[19];
    const float* cls_w    = (const float*)d_in[20];
    const float* cls_b    = (const float*)d_in[21];

    const int M = BS * LSEQ;             // 2048 rows
    float* ws  = (float*)d_ws;
    float* h   = ws;                      // 524288
    float* hn  = h   + (long)M*DM;        // 524288
    float* xz  = hn  + (long)M*DM;        // 2*2048*1024 = 4194304
    float* xc  = xz  + (long)2*M*1024;    // 2*2048*512  = 2097152
    float* xdb = xc  + (long)2*M*DIc;     // 2*2048*80   = 327680
    float* dtb = xdb + (long)2*M*80;      // 2*2048*512  = 2097152
    float* yb  = dtb + (long)2*M*DIc;     // 2*2048*512  = 2097152
    float* mo  = yb  + (long)2*M*DIc;     // 2048*512    = 1048576

    // patch embed + input LN -> h
    patch_k<<<M, 256, 0, stream>>>(x, patch_w, patch_b, in_g, in_b, h);

    for (int i = 0; i < NLAY; ++i) {
        const float* ipw = in_proj_w + (long)i*2*DM*1024;
        const float* cw  = conv_w    + (long)i*2*DIc*4;
        const float* cb  = conv_b    + (long)i*2*DIc;
        const float* xpw = x_proj_w  + (long)i*2*DIc*80;
        const float* dtw = dt_proj_w + (long)i*2*DTR*DIc;
        const float* dtbias = dt_proj_b + (long)i*2*DIc;
        const float* Al  = A_log     + (long)i*2*DIc*DSt;
        const float* Dvp = Dv        + (long)i*2*DIc;
        const float* mow = m_out_w   + (long)i*2*DIc*DM;
        const float* bow = blk_out_w + (long)i*DIc*DM;
        const float* bob = blk_out_b + (long)i*DM;

        // hn = LN(h)
        ln_k<<<M, 256, 0, stream>>>(h, ln_g + i*DM, ln_b + i*DM, hn);

        // xz[dir] = hn @ in_proj_w[i,dir]   (M=2048, K=256, N=1024)
        gemm_k<0,0><<<dim3(1024/BN, M/BM, 2), 256, 0, stream>>>(
            hn, 0, DM,  nullptr, 0, 0,
            ipw, (long)DM*1024, 1024,
            nullptr, 0, nullptr, 0,
            xz, (long)M*1024, 1024, M, 1024, DM);

        // xc[dir] (scan order) = silu(depthwise_causal_conv(xpart) + cb)
        conv_silu_k<<<(2L*M*DIc)/256, 256, 0, stream>>>(xz, cw, cb, xc);

        // xdbl[dir] = xc @ x_proj_w[i,dir]  (M=2048, K=512, N=80)
        gemm_k<0,0><<<dim3(2, M/BM, 2), 256, 0, stream>>>(
            xc, (long)M*DIc, DIc,  nullptr, 0, 0,
            xpw, (long)DIc*80, 80,
            nullptr, 0, nullptr, 0,
            xdb, (long)M*80, 80, M, 80, DIc);

        // dt = softplus(xdbl[:, :16] @ dt_proj_w + dt_proj_b)  (M=2048, K=16, N=512)
        gemm_k<0,1><<<dim3(DIc/BN, M/BM, 2), 256, 0, stream>>>(
            xdb, (long)M*80, 80,  nullptr, 0, 0,
            dtw, (long)DTR*DIc, DIc,
            dtbias, DIc, nullptr, 0,
            dtb, (long)M*DIc, DIc, M, DIc, DTR);

        // selective scan -> yb (original time order), includes +xc*Dv
        scan_k<<<dim3(DIc/8, BS, 2), 256, 0, stream>>>(dtb, xc, xdb, Al, Dvp, yb);

        // mo[:, dir*256:(dir+1)*256] = (yb * silu(z)) @ m_out_w[i,dir]
        gemm_k<1,0><<<dim3(DM/BN, M/BM, 2), 256, 0, stream>>>(
            yb, (long)M*DIc, DIc,
            xz + DIc, (long)M*1024, 1024,      // z = xz[..., 512:]
            mow, (long)DIc*DM, DM,
            nullptr, 0, nullptr, 0,
            mo, DM, DIc, M, DM, DIc);

        // h = mo @ blk_out_w[i] + blk_out_b[i] + h   (M=2048, K=512, N=256)
        gemm_k<0,2><<<dim3(DM/BN, M/BM, 1), 256, 0, stream>>>(
            mo, 0, DIc,  nullptr, 0, 0,
            bow, 0, DM,
            bob, 0, h, DM,
            h, 0, DM, M, DM, DIc);
    }

    // final LN + head
    ln_k<<<M, 256, 0, stream>>>(h, fin_g, fin_b, hn);
    head_k<<<BS, 256, 0, stream>>>(hn, cls_w, cls_b, (float*)d_out);
}

// Round 3
// 1592.394 us; speedup vs baseline: 2.2158x; 1.1911x over previous
//
#include <hip/hip_runtime.h>
#include <math.h>

#define BS  4
#define LSEQ 512
#define DM  256
#define DIc 512
#define DSt 32
#define DTR 16
#define NLAY 6
#define NCLS 50
#define PATCH 160
#define NCH 8
#define CL  64

__device__ __forceinline__ float sigmoidf_(float x){ return 1.f/(1.f+__expf(-x)); }
__device__ __forceinline__ float siluf_(float x){ return x*sigmoidf_(x); }
__device__ __forceinline__ float softplusf_(float x){ return fmaxf(x,0.f) + log1pf(expf(-fabsf(x))); }

typedef __attribute__((ext_vector_type(8))) short bf16x8;
typedef __attribute__((ext_vector_type(4))) float floatx4;

__device__ __forceinline__ unsigned short f2bf(float f){
    union { float f; unsigned int u; } v; v.f = f;
    unsigned int r = v.u + 0x7fffu + ((v.u >> 16) & 1u);
    return (unsigned short)(r >> 16);
}
__device__ __forceinline__ float bf2f(unsigned short h){
    union { float f; unsigned int u; } v; v.u = ((unsigned int)h) << 16;
    return v.f;
}

// ---------------- LayerNorm over last dim (256) --------------------------------
__global__ __launch_bounds__(256) void ln_k(const float* __restrict__ in,
                                            const float* __restrict__ g,
                                            const float* __restrict__ bta,
                                            float* __restrict__ out)
{
    int row = blockIdx.x;
    int c = threadIdx.x;
    float v = in[(long)row*DM + c];
    __shared__ float red[4];
    __shared__ float mu_s, rs_s;
    float s = v;
    #pragma unroll
    for (int o = 32; o; o >>= 1) s += __shfl_down(s, o);
    if ((threadIdx.x & 63) == 0) red[threadIdx.x >> 6] = s;
    __syncthreads();
    if (threadIdx.x == 0) mu_s = (red[0]+red[1]+red[2]+red[3]) * (1.f/DM);
    __syncthreads();
    float mu = mu_s;
    float d0 = v - mu;
    float q = d0*d0;
    #pragma unroll
    for (int o = 32; o; o >>= 1) q += __shfl_down(q, o);
    if ((threadIdx.x & 63) == 0) red[threadIdx.x >> 6] = q;
    __syncthreads();
    if (threadIdx.x == 0) rs_s = rsqrtf((red[0]+red[1]+red[2]+red[3]) * (1.f/DM) + 1e-5f);
    __syncthreads();
    out[(long)row*DM + c] = d0 * rs_s * g[c] + bta[c];
}

// ---------------- Patch conv + bias + LayerNorm --------------------------------
__global__ __launch_bounds__(256) void patch_k(const float* __restrict__ x,
                                               const float* __restrict__ pw,
                                               const float* __restrict__ pb,
                                               const float* __restrict__ g,
                                               const float* __restrict__ bta,
                                               float* __restrict__ out)
{
    int bl = blockIdx.x;
    int b = bl >> 9, l = bl & 511;
    __shared__ float xs[PATCH];
    if (threadIdx.x < PATCH) xs[threadIdx.x] = x[(long)b*81920 + l*PATCH + threadIdx.x];
    __syncthreads();
    int c = threadIdx.x;
    float acc = pb[c];
    const float* w = pw + (long)c*PATCH;
    #pragma unroll 4
    for (int k = 0; k < PATCH; ++k) acc = fmaf(xs[k], w[k], acc);
    __shared__ float red[4];
    __shared__ float mu_s, rs_s;
    float s = acc;
    #pragma unroll
    for (int o = 32; o; o >>= 1) s += __shfl_down(s, o);
    if ((threadIdx.x & 63) == 0) red[threadIdx.x >> 6] = s;
    __syncthreads();
    if (threadIdx.x == 0) mu_s = (red[0]+red[1]+red[2]+red[3]) * (1.f/DM);
    __syncthreads();
    float mu = mu_s;
    float d0 = acc - mu;
    float q = d0*d0;
    #pragma unroll
    for (int o = 32; o; o >>= 1) q += __shfl_down(q, o);
    if ((threadIdx.x & 63) == 0) red[threadIdx.x >> 6] = q;
    __syncthreads();
    if (threadIdx.x == 0) rs_s = rsqrtf((red[0]+red[1]+red[2]+red[3]) * (1.f/DM) + 1e-5f);
    __syncthreads();
    out[(long)bl*DM + c] = d0 * rs_s * g[c] + bta[c];
}

// ---------------- Generic tiled fp32 GEMM (kept for small GEMMs + fallback) ----
#define BM 64
#define BN 64
#define BK 16
template<int AMODE, int EMODE>
__global__ __launch_bounds__(256) void gemm_k(
    const float* __restrict__ A,  long aZ, int lda,
    const float* __restrict__ A2, long a2Z, int lda2,
    const float* __restrict__ Bw, long bZ, int ldb,
    const float* __restrict__ bias, long biasZ,
    const float* __restrict__ Res, int ldres,
    float* __restrict__ C, long cZ, int ldc,
    int M, int N, int K)
{
    int z = blockIdx.z;
    A += (long)z * aZ;
    if (AMODE == 1) A2 += (long)z * a2Z;
    Bw += (long)z * bZ;
    if (EMODE >= 1) bias += (long)z * biasZ;
    C += (long)z * cZ;

    __shared__ float As[2][BK][BM+4];
    __shared__ float Bs[2][BK][BN];
    int row0 = blockIdx.y * BM, col0 = blockIdx.x * BN;
    int tx = threadIdx.x & 15, ty = threadIdx.x >> 4;
    float acc[4][4] = {};

    {
        #pragma unroll
        for (int e = 0; e < 4; ++e) {
            int idx = e*256 + threadIdx.x;
            int m = idx >> 4, kk = idx & 15;
            int gr = row0 + m, gk = kk;
            float v = 0.f;
            if (gr < M && gk < K) {
                v = A[(long)gr*lda + gk];
                if (AMODE == 1) v *= siluf_(A2[(long)gr*lda2 + gk]);
            }
            As[0][kk][m] = v;
            int kb = idx >> 6, nn = idx & 63;
            int gn = col0 + nn;
            Bs[0][kb][nn] = (kb < K && gn < N) ? Bw[(long)kb*ldb + gn] : 0.f;
        }
    }
    __syncthreads();

    int nbuf = 1;
    for (int k0 = 0; k0 < K; k0 += BK) {
        int cur = nbuf ^ 1;
        bool more = (k0 + BK) < K;
        float ra[4], rb[4];
        if (more) {
            #pragma unroll
            for (int e = 0; e < 4; ++e) {
                int idx = e*256 + threadIdx.x;
                int m = idx >> 4, kk = idx & 15;
                int gr = row0 + m, gk = k0 + BK + kk;
                float v = 0.f;
                if (gr < M && gk < K) {
                    v = A[(long)gr*lda + gk];
                    if (AMODE == 1) v *= siluf_(A2[(long)gr*lda2 + gk]);
                }
                ra[e] = v;
                int kb = idx >> 6, nn = idx & 63;
                int gk2 = k0 + BK + kb, gn = col0 + nn;
                rb[e] = (gk2 < K && gn < N) ? Bw[(long)gk2*ldb + gn] : 0.f;
            }
        }
        #pragma unroll
        for (int kk = 0; kk < BK; ++kk) {
            float4 av = *reinterpret_cast<const float4*>(&As[cur][kk][ty*4]);
            float4 bv = *reinterpret_cast<const float4*>(&Bs[cur][kk][tx*4]);
            float a[4] = {av.x, av.y, av.z, av.w};
            float b[4] = {bv.x, bv.y, bv.z, bv.w};
            #pragma unroll
            for (int i = 0; i < 4; ++i)
                #pragma unroll
                for (int j = 0; j < 4; ++j)
                    acc[i][j] = fmaf(a[i], b[j], acc[i][j]);
        }
        if (more) {
            #pragma unroll
            for (int e = 0; e < 4; ++e) {
                int idx = e*256 + threadIdx.x;
                As[nbuf][idx & 15][idx >> 4] = ra[e];
                Bs[nbuf][idx >> 6][idx & 63] = rb[e];
            }
        }
        __syncthreads();
        nbuf ^= 1;
    }

    #pragma unroll
    for (int i = 0; i < 4; ++i) {
        int gr = row0 + ty*4 + i;
        if (gr >= M) continue;
        #pragma unroll
        for (int j = 0; j < 4; ++j) {
            int gn = col0 + tx*4 + j;
            if (gn >= N) continue;
            float v = acc[i][j];
            if (EMODE == 1)      v = softplusf_(v + bias[gn]);
            else if (EMODE == 2) v = v + bias[gn] + Res[(long)gr*ldres + gn];
            C[(long)gr*ldc + gn] = v;
        }
    }
}

// ---------------- Weight prep: fp32 [K][N] -> bf16 hi/lo planes [N][K] ----------
__global__ __launch_bounds__(256) void wprep_k(const float* __restrict__ src,
                                               unsigned short* __restrict__ dhi,
                                               unsigned short* __restrict__ dlo,
                                               int K, int N)
{
    long mo = (long)blockIdx.z * K * N;
    src += mo; dhi += mo; dlo += mo;
    int k0 = blockIdx.y * 64, n0 = blockIdx.x * 64;
    __shared__ float ls[64][65];
    int t = threadIdx.x;
    int kk = t >> 4, nn4 = (t & 15) * 4;
    #pragma unroll
    for (int r = 0; r < 4; ++r) {
        float4 v = *(const float4*)(src + (long)(k0 + kk + r*16)*N + n0 + nn4);
        ls[kk + r*16][nn4+0] = v.x; ls[kk + r*16][nn4+1] = v.y;
        ls[kk + r*16][nn4+2] = v.z; ls[kk + r*16][nn4+3] = v.w;
    }
    __syncthreads();
    int nrow = t >> 4, kcol = (t & 15) * 4;
    #pragma unroll
    for (int r = 0; r < 4; ++r) {
        int nr = nrow + r*16;
        ushort4 h4, l4;
        float v0 = ls[kcol+0][nr], v1 = ls[kcol+1][nr], v2 = ls[kcol+2][nr], v3 = ls[kcol+3][nr];
        h4.x = f2bf(v0); l4.x = f2bf(v0 - bf2f(h4.x));
        h4.y = f2bf(v1); l4.y = f2bf(v1 - bf2f(h4.y));
        h4.z = f2bf(v2); l4.z = f2bf(v2 - bf2f(h4.z));
        h4.w = f2bf(v3); l4.w = f2bf(v3 - bf2f(h4.w));
        *(ushort4*)(dhi + (long)(n0 + nr)*K + k0 + kcol) = h4;
        *(ushort4*)(dlo + (long)(n0 + nr)*K + k0 + kcol) = l4;
    }
}

// ---------------- bf16x3 MFMA GEMM ---------------------------------------------
// C = epilogue(A @ B), A fp32 [M][K] (M mult 64), B prepped bf16 [N][K] hi/lo.
// AMODE 1: a *= silu(A2). EMODE 2: C = acc + bias + Res.
template<int AMODE, int EMODE>
__global__ __launch_bounds__(256) void gemm_mfma_k(
    const float* __restrict__ A, long aZ, int lda,
    const float* __restrict__ A2, long a2Z, int lda2,
    const unsigned short* __restrict__ BtH, const unsigned short* __restrict__ BtL, long bZ,
    const float* __restrict__ bias, long biasZ,
    const float* __restrict__ Res, int ldres,
    float* __restrict__ C, long cZ, int ldc,
    int K)
{
    int z = blockIdx.z;
    A += (long)z * aZ;
    if (AMODE == 1) A2 += (long)z * a2Z;
    BtH += (long)z * bZ; BtL += (long)z * bZ;
    if (EMODE >= 1) bias += (long)z * biasZ;
    C += (long)z * cZ;

    __shared__ unsigned short AsH[64][40], AsL[64][40], BsH[64][40], BsL[64][40];
    int t = threadIdx.x;
    int lane = t & 63, wave = t >> 6;
    int quad = lane >> 4, l15 = lane & 15;
    int wm = (wave & 1) * 32, wn = (wave >> 1) * 32;
    long row0 = (long)blockIdx.y * 64, col0 = (long)blockIdx.x * 64;

    int ar = t >> 2, ac = (t & 3) * 8;     // A staging: row, k-offset
    int bn = t >> 2, bk = (t & 3) * 8;     // B staging

    const float* Arow  = A + (row0 + ar)*lda + ac;
    const float* A2row = (AMODE == 1) ? (A2 + (row0 + ar)*lda2 + ac) : A;
    const unsigned short* BHrow = BtH + (col0 + bn)*(long)K + bk;
    const unsigned short* BLrow = BtL + (col0 + bn)*(long)K + bk;

    floatx4 acc[2][2] = {};

    for (int k0 = 0; k0 < K; k0 += 32) {
        float4 a0 = *(const float4*)(Arow + k0);
        float4 a1 = *(const float4*)(Arow + k0 + 4);
        if (AMODE == 1) {
            float4 g0 = *(const float4*)(A2row + k0);
            float4 g1 = *(const float4*)(A2row + k0 + 4);
            a0.x *= siluf_(g0.x); a0.y *= siluf_(g0.y); a0.z *= siluf_(g0.z); a0.w *= siluf_(g0.w);
            a1.x *= siluf_(g1.x); a1.y *= siluf_(g1.y); a1.z *= siluf_(g1.z); a1.w *= siluf_(g1.w);
        }
        bf16x8 ah, al;
        float av[8] = {a0.x,a0.y,a0.z,a0.w,a1.x,a1.y,a1.z,a1.w};
        #pragma unroll
        for (int i = 0; i < 8; ++i) {
            unsigned short h = f2bf(av[i]);
            ah[i] = (short)h;
            al[i] = (short)f2bf(av[i] - bf2f(h));
        }
        bf16x8 bh = *(const bf16x8*)(BHrow + k0);
        bf16x8 bl = *(const bf16x8*)(BLrow + k0);
        *(bf16x8*)&AsH[ar][ac] = ah;
        *(bf16x8*)&AsL[ar][ac] = al;
        *(bf16x8*)&BsH[bn][bk] = bh;
        *(bf16x8*)&BsL[bn][bk] = bl;
        __syncthreads();

        bf16x8 fAh[2], fAl[2], fBh[2], fBl[2];
        #pragma unroll
        for (int mt = 0; mt < 2; ++mt) {
            fAh[mt] = *(const bf16x8*)&AsH[wm + mt*16 + l15][quad*8];
            fAl[mt] = *(const bf16x8*)&AsL[wm + mt*16 + l15][quad*8];
        }
        #pragma unroll
        for (int nt = 0; nt < 2; ++nt) {
            fBh[nt] = *(const bf16x8*)&BsH[wn + nt*16 + l15][quad*8];
            fBl[nt] = *(const bf16x8*)&BsL[wn + nt*16 + l15][quad*8];
        }
        #pragma unroll
        for (int mt = 0; mt < 2; ++mt)
            #pragma unroll
            for (int nt = 0; nt < 2; ++nt) {
                acc[mt][nt] = __builtin_amdgcn_mfma_f32_16x16x32_bf16(fAh[mt], fBh[nt], acc[mt][nt], 0, 0, 0);
                acc[mt][nt] = __builtin_amdgcn_mfma_f32_16x16x32_bf16(fAh[mt], fBl[nt], acc[mt][nt], 0, 0, 0);
                acc[mt][nt] = __builtin_amdgcn_mfma_f32_16x16x32_bf16(fAl[mt], fBh[nt], acc[mt][nt], 0, 0, 0);
            }
        __syncthreads();
    }

    #pragma unroll
    for (int mt = 0; mt < 2; ++mt)
        #pragma unroll
        for (int nt = 0; nt < 2; ++nt) {
            long col = col0 + wn + nt*16 + l15;
            #pragma unroll
            for (int r = 0; r < 4; ++r) {
                long row = row0 + wm + mt*16 + quad*4 + r;
                float v = acc[mt][nt][r];
                if (EMODE == 2) v += bias[col] + Res[row*ldres + col];
                C[row*ldc + col] = v;
            }
        }
}

// ---------------- Depthwise causal conv (k=4) + bias + SiLU --------------------
__global__ __launch_bounds__(256) void conv_silu_k(const float* __restrict__ xz,
                                                   const float* __restrict__ cw,
                                                   const float* __restrict__ cb,
                                                   float* __restrict__ xc)
{
    long idx = (long)blockIdx.x * 256 + threadIdx.x;
    int d   = idx & 511;
    int s   = (idx >> 9) & 511;
    int b   = (idx >> 18) & 3;
    int dir = (int)(idx >> 20);
    const float* xp = xz + (((long)dir*BS + b) * LSEQ) * 1024;
    float acc = cb[dir*DIc + d];
    const float* w = cw + ((long)dir*DIc + d) * 4;
    #pragma unroll
    for (int j = 0; j < 4; ++j) {
        int m = s - 3 + j;
        if (m >= 0) {
            int t = dir ? (LSEQ-1 - m) : m;
            acc = fmaf(w[j], xp[(long)t*1024 + d], acc);
        }
    }
    xc[idx] = siluf_(acc);
}

// ---------------- Selective scan, chunked two-pass ------------------------------
// scanA: per-chunk local scan. Also rewrites dt buffer in place with the
// within-chunk prefix sum of dt (needed by scanC), stores chunk end-state and
// chunk decay product.
#define TCH 8
__global__ __launch_bounds__(256) void scanA_k(float* __restrict__ dt,        // [2][BS][s][DIc], becomes cumdt
                                               const float* __restrict__ u,    // xc
                                               const float* __restrict__ xdbl, // [2][BS][s][80]
                                               const float* __restrict__ A_log,
                                               const float* __restrict__ Dv,
                                               float* __restrict__ y,          // [2][BS][t][DIc] (partial)
                                               float* __restrict__ hend,       // [8zz][8ch][DIc][32]
                                               float* __restrict__ aend)
{
    int zz = blockIdx.z;                 // dir*4 + b
    int dir = zz >> 2, b = zz & 3;
    int ch = blockIdx.y;
    int n = threadIdx.x & 31;
    int d = blockIdx.x * 8 + (threadIdx.x >> 5);
    float Adn = -__expf(A_log[((long)dir*DIc + d)*DSt + n]);
    float Dd  = Dv[dir*DIc + d];
    long base = ((long)dir*BS + b) * LSEQ;
    float* dtp = dt + (base + (long)ch*CL)*DIc + d;
    const float* up  = u  + (base + (long)ch*CL)*DIc + d;
    const float* xdp = xdbl + (base + (long)ch*CL)*80;
    float* yp = y + base*DIc + d;
    int sg0 = ch*CL;

    float cdt[TCH], cu[TCH], cB[TCH], cC[TCH];
    float ndt[TCH], nu[TCH], nB[TCH], nC[TCH];
    #pragma unroll
    for (int j = 0; j < TCH; ++j) {
        cdt[j] = dtp[(long)j*DIc];
        cu[j]  = up[(long)j*DIc];
        cB[j]  = xdp[j*80 + 16 + n];
        cC[j]  = xdp[j*80 + 48 + n];
    }

    float h = 0.f, sumdt = 0.f;
    for (int s0 = 0; s0 < CL; s0 += TCH) {
        int s1 = s0 + TCH;
        bool more = s1 < CL;
        if (more) {
            #pragma unroll
            for (int j = 0; j < TCH; ++j) {
                ndt[j] = dtp[(long)(s1+j)*DIc];
                nu[j]  = up[(long)(s1+j)*DIc];
                nB[j]  = xdp[(s1+j)*80 + 16 + n];
                nC[j]  = xdp[(s1+j)*80 + 48 + n];
            }
        }
        float da[TCH], bu[TCH], p[TCH], pre[TCH];
        #pragma unroll
        for (int j = 0; j < TCH; ++j) {
            da[j] = __expf(cdt[j]*Adn);
            bu[j] = cdt[j]*cu[j]*cB[j];
        }
        #pragma unroll
        for (int j = 0; j < TCH; ++j) {
            sumdt += cdt[j];
            pre[j] = sumdt;
            h = fmaf(da[j], h, bu[j]);
            p[j] = h * cC[j];
        }
        #pragma unroll
        for (int st = 1; st < 32; st <<= 1) {
            #pragma unroll
            for (int j = 0; j < TCH; ++j)
                p[j] += __shfl_xor(p[j], st, 32);
        }
        float outv = 0.f, cst = 0.f;
        #pragma unroll
        for (int j = 0; j < TCH; ++j)
            if (n == j) { outv = fmaf(cu[j], Dd, p[j]); cst = pre[j]; }
        if (n < TCH) {
            int sg = sg0 + s0 + n;
            int tt = dir ? (LSEQ-1 - sg) : sg;
            yp[(long)tt*DIc] = outv;
            dtp[(long)(s0+n)*DIc] = cst;     // in-place cumdt (reads already done)
        }
        if (more) {
            #pragma unroll
            for (int j = 0; j < TCH; ++j) {
                cdt[j]=ndt[j]; cu[j]=nu[j]; cB[j]=nB[j]; cC[j]=nC[j];
            }
        }
    }
    long o = (((long)zz*NCH + ch)*DIc + d)*DSt + n;
    hend[o] = h;
    aend[o] = __expf(Adn * sumdt);
}

// scanC: propagate chunk boundary states, add correction to y.
__global__ __launch_bounds__(256) void scanC_k(const float* __restrict__ cumdt,
                                               const float* __restrict__ xdbl,
                                               const float* __restrict__ A_log,
                                               const float* __restrict__ hend,
                                               const float* __restrict__ aend,
                                               float* __restrict__ y)
{
    int zz = blockIdx.z;
    int dir = zz >> 2, b = zz & 3;
    int ch = blockIdx.y + 1;
    int n = threadIdx.x & 31;
    int d = blockIdx.x * 8 + (threadIdx.x >> 5);
    float Adn = -__expf(A_log[((long)dir*DIc + d)*DSt + n]);
    float H = 0.f;
    for (int j = 0; j < ch; ++j) {
        long o = (((long)zz*NCH + j)*DIc + d)*DSt + n;
        H = fmaf(aend[o], H, hend[o]);
    }
    long base = ((long)dir*BS + b) * LSEQ;
    const float* cp  = cumdt + (base + (long)ch*CL)*DIc + d;
    const float* xdp = xdbl  + (base + (long)ch*CL)*80;
    float* yp = y + base*DIc + d;
    int sg0 = ch*CL;

    float cc[TCH], cC[TCH], nc[TCH], nC[TCH];
    #pragma unroll
    for (int j = 0; j < TCH; ++j) {
        cc[j] = cp[(long)j*DIc];
        cC[j] = xdp[j*80 + 48 + n];
    }
    for (int s0 = 0; s0 < CL; s0 += TCH) {
        int s1 = s0 + TCH;
        bool more = s1 < CL;
        if (more) {
            #pragma unroll
            for (int j = 0; j < TCH; ++j) {
                nc[j] = cp[(long)(s1+j)*DIc];
                nC[j] = xdp[(s1+j)*80 + 48 + n];
            }
        }
        float p[TCH];
        #pragma unroll
        for (int j = 0; j < TCH; ++j)
            p[j] = __expf(Adn*cc[j]) * H * cC[j];
        #pragma unroll
        for (int st = 1; st < 32; st <<= 1) {
            #pragma unroll
            for (int j = 0; j < TCH; ++j)
                p[j] += __shfl_xor(p[j], st, 32);
        }
        float addv = 0.f;
        #pragma unroll
        for (int j = 0; j < TCH; ++j)
            if (n == j) addv = p[j];
        if (n < TCH) {
            int sg = sg0 + s0 + n;
            int tt = dir ? (LSEQ-1 - sg) : sg;
            yp[(long)tt*DIc] += addv;
        }
        if (more) {
            #pragma unroll
            for (int j = 0; j < TCH; ++j) { cc[j]=nc[j]; cC[j]=nC[j]; }
        }
    }
}

// ---------------- Head ----------------------------------------------------------
__global__ __launch_bounds__(256) void head_k(const float* __restrict__ hn,
                                              const float* __restrict__ cw,
                                              const float* __restrict__ cb2,
                                              float* __restrict__ out)
{
    int b = blockIdx.x;
    int c = threadIdx.x;
    float acc = 0.f;
    for (int t = 0; t < LSEQ; ++t) acc += hn[((long)b*LSEQ + t)*DM + c];
    __shared__ float mv[DM];
    mv[c] = acc * (1.f/LSEQ);
    __syncthreads();
    if (c < NCLS) {
        float o = cb2[c];
        #pragma unroll 4
        for (int k = 0; k < DM; ++k) o = fmaf(mv[k], cw[k*NCLS + c], o);
        out[b*NCLS + c] = o;
    }
}

extern "C" void kernel_launch(void* const* d_in, const int* in_sizes, int n_in,
                              void* d_out, int out_size, void* d_ws, size_t ws_size,
                              hipStream_t stream)
{
    const float* x        = (const float*)d_in[0];
    const float* patch_w  = (const float*)d_in[1];
    const float* patch_b  = (const float*)d_in[2];
    const float* in_g     = (const float*)d_in[3];
    const float* in_b     = (const float*)d_in[4];
    const float* ln_g     = (const float*)d_in[5];
    const float* ln_b     = (const float*)d_in[6];
    const float* in_proj_w= (const float*)d_in[7];
    const float* conv_w   = (const float*)d_in[8];
    const float* conv_b   = (const float*)d_in[9];
    const float* x_proj_w = (const float*)d_in[10];
    const float* dt_proj_w= (const float*)d_in[11];
    const float* dt_proj_b= (const float*)d_in[12];
    const float* A_log    = (const float*)d_in[13];
    const float* Dv       = (const float*)d_in[14];
    const float* m_out_w  = (const float*)d_in[15];
    const float* blk_out_w= (const float*)d_in[16];
    const float* blk_out_b= (const float*)d_in[17];
    const float* fin_g    = (const float*)d_in[18];
    const float* fin_b    = (const float*)d_in[19];
    const float* cls_w    = (const float*)d_in[20];
    const float* cls_b    = (const float*)d_in[21];

    const int M = BS * LSEQ;             // 2048
    float* ws  = (float*)d_ws;
    float* h    = ws;                     //   524288
    float* hn   = h   + (long)M*DM;       //   524288
    float* xz   = hn  + (long)M*DM;       // 4194304
    float* xc   = xz  + (long)2*M*1024;   // 2097152
    float* xdb  = xc  + (long)2*M*DIc;    //  327680
    float* dtb  = xdb + (long)2*M*80;     // 2097152 (dt -> cumdt in place)
    float* yb   = dtb + (long)2*M*DIc;    // 2097152
    float* mo   = yb  + (long)2*M*DIc;    // 1048576 (aliased as hend during scan)
    float* aend = mo  + (long)M*DIc;      // 1048576
    float* hend = mo;                     // alias: mo dead during scan
    unsigned short* wb = (unsigned short*)(aend + (long)2*NCH*8*DIc*DSt/2 + 524288); // see below

    // weight blob layout (ushort), after aend:
    // aend size = 8*8*512*32 = 1,048,576 floats
    unsigned short* wbase = (unsigned short*)(aend + 1048576);
    const long XZSZ  = 1024L*256;   // per (layer,dir)
    const long OUTSZ = 256L*512;
    const long BLKSZ = 256L*512;
    unsigned short* wxzH  = wbase;
    unsigned short* wxzL  = wxzH  + 12*XZSZ;
    unsigned short* woutH = wxzL  + 12*XZSZ;
    unsigned short* woutL = woutH + 12*OUTSZ;
    unsigned short* wblkH = woutL + 12*OUTSZ;
    unsigned short* wblkL = wblkH + 6*BLKSZ;
    size_t req = (size_t)((char*)(wblkL + 6*BLKSZ) - (char*)d_ws);
    bool use_mfma = ws_size >= req;
    (void)wb;

    patch_k<<<M, 256, 0, stream>>>(x, patch_w, patch_b, in_g, in_b, h);

    if (use_mfma) {
        wprep_k<<<dim3(1024/64, 256/64, 12), 256, 0, stream>>>(in_proj_w, wxzH, wxzL, 256, 1024);
        wprep_k<<<dim3(256/64, 512/64, 12), 256, 0, stream>>>(m_out_w, woutH, woutL, 512, 256);
        wprep_k<<<dim3(256/64, 512/64,  6), 256, 0, stream>>>(blk_out_w, wblkH, wblkL, 512, 256);
    }

    for (int i = 0; i < NLAY; ++i) {
        const float* ipw = in_proj_w + (long)i*2*DM*1024;
        const float* cw  = conv_w    + (long)i*2*DIc*4;
        const float* cb  = conv_b    + (long)i*2*DIc;
        const float* xpw = x_proj_w  + (long)i*2*DIc*80;
        const float* dtw = dt_proj_w + (long)i*2*DTR*DIc;
        const float* dtbias = dt_proj_b + (long)i*2*DIc;
        const float* Al  = A_log     + (long)i*2*DIc*DSt;
        const float* Dvp = Dv        + (long)i*2*DIc;
        const float* mow = m_out_w   + (long)i*2*DIc*DM;
        const float* bow = blk_out_w + (long)i*DIc*DM;
        const float* bob = blk_out_b + (long)i*DM;

        ln_k<<<M, 256, 0, stream>>>(h, ln_g + i*DM, ln_b + i*DM, hn);

        // xz[dir] = hn @ in_proj_w[i,dir]   (M=2048, N=1024, K=256)
        if (use_mfma) {
            gemm_mfma_k<0,0><<<dim3(16, 32, 2), 256, 0, stream>>>(
                hn, 0, DM, nullptr, 0, 0,
                wxzH + (long)i*2*XZSZ, wxzL + (long)i*2*XZSZ, XZSZ,
                nullptr, 0, nullptr, 0,
                xz, (long)M*1024, 1024, DM);
        } else {
            gemm_k<0,0><<<dim3(1024/BN, M/BM, 2), 256, 0, stream>>>(
                hn, 0, DM, nullptr, 0, 0, ipw, (long)DM*1024, 1024,
                nullptr, 0, nullptr, 0, xz, (long)M*1024, 1024, M, 1024, DM);
        }

        conv_silu_k<<<(2L*M*DIc)/256, 256, 0, stream>>>(xz, cw, cb, xc);

        // xdbl[dir] = xc @ x_proj_w[i,dir]  (M=2048, N=80, K=512)
        gemm_k<0,0><<<dim3(2, M/BM, 2), 256, 0, stream>>>(
            xc, (long)M*DIc, DIc, nullptr, 0, 0,
            xpw, (long)DIc*80, 80,
            nullptr, 0, nullptr, 0,
            xdb, (long)M*80, 80, M, 80, DIc);

        // dt = softplus(xdbl[:, :16] @ dt_proj_w + b)  (M=2048, N=512, K=16)
        gemm_k<0,1><<<dim3(DIc/BN, M/BM, 2), 256, 0, stream>>>(
            xdb, (long)M*80, 80, nullptr, 0, 0,
            dtw, (long)DTR*DIc, DIc,
            dtbias, DIc, nullptr, 0,
            dtb, (long)M*DIc, DIc, M, DIc, DTR);

        // chunked scan
        scanA_k<<<dim3(DIc/8, NCH, 8), 256, 0, stream>>>(dtb, xc, xdb, Al, Dvp, yb, hend, aend);
        scanC_k<<<dim3(DIc/8, NCH-1, 8), 256, 0, stream>>>(dtb, xdb, Al, hend, aend, yb);

        // mo[:, dir*256:] = (yb * silu(z)) @ m_out_w[i,dir]  (N=256, K=512)
        if (use_mfma) {
            gemm_mfma_k<1,0><<<dim3(4, 32, 2), 256, 0, stream>>>(
                yb, (long)M*DIc, DIc,
                xz + DIc, (long)M*1024, 1024,
                woutH + (long)i*2*OUTSZ, woutL + (long)i*2*OUTSZ, OUTSZ,
                nullptr, 0, nullptr, 0,
                mo, DM, DIc, DIc);
        } else {
            gemm_k<1,0><<<dim3(DM/BN, M/BM, 2), 256, 0, stream>>>(
                yb, (long)M*DIc, DIc, xz + DIc, (long)M*1024, 1024,
                mow, (long)DIc*DM, DM, nullptr, 0, nullptr, 0,
                mo, DM, DIc, M, DM, DIc);
        }

        // h = mo @ blk_out_w[i] + bias + h  (N=256, K=512)
        if (use_mfma) {
            gemm_mfma_k<0,2><<<dim3(4, 32, 1), 256, 0, stream>>>(
                mo, 0, DIc, nullptr, 0, 0,
                wblkH + (long)i*BLKSZ, wblkL + (long)i*BLKSZ, 0,
                bob, 0, h, DM,
                h, 0, DM, DIc);
        } else {
            gemm_k<0,2><<<dim3(DM/BN, M/BM, 1), 256, 0, stream>>>(
                mo, 0, DIc, nullptr, 0, 0, bow, 0, DM,
                bob, 0, h, DM, h, 0, DM, M, DM, DIc);
        }
    }

    ln_k<<<M, 256, 0, stream>>>(h, fin_g, fin_b, hn);
    head_k<<<BS, 256, 0, stream>>>(hn, cls_w, cls_b, (float*)d_out);
}